// Round 12
// baseline (135.745 us; speedup 1.0000x reference)
//
#include <hip/hip_runtime.h>
#include <math.h>

#define N 8192
#define D 256
#define QBLK 128          // 4 waves x 32 q-rows
#define KBLK 32

typedef float f32x4 __attribute__((ext_vector_type(4)));
typedef float f32x16 __attribute__((ext_vector_type(16)));
typedef short bf16x8 __attribute__((ext_vector_type(8)));

#define MFMA16(a, b, c) __builtin_amdgcn_mfma_f32_16x16x32_bf16((a), (b), (c), 0, 0, 0)
#define MFMA32(a, b, c) __builtin_amdgcn_mfma_f32_32x32x16_bf16((a), (b), (c), 0, 0, 0)
#define BAR() __builtin_amdgcn_s_barrier()
#define CFENCE() asm volatile("" ::: "memory")

__device__ __forceinline__ unsigned short f2b(float f) {
    unsigned u = __builtin_bit_cast(unsigned, f);
    u = u + 0x7fffu + ((u >> 16) & 1u);            // RNE
    return (unsigned short)(u >> 16);
}
__device__ __forceinline__ unsigned pk2(float a, float b) {
    return (unsigned)f2b(a) | ((unsigned)f2b(b) << 16);
}
__device__ __forceinline__ unsigned cvtpk(float a, float b) {
    unsigned r;
    asm("v_cvt_pk_bf16_f32 %0, %1, %2" : "=v"(r) : "v"(a), "v"(b));
    return r;
}
__device__ __forceinline__ float b2f(short s) {
    unsigned x = ((unsigned)(unsigned short)s) << 16;
    return __builtin_bit_cast(float, x);
}

// ---------------------------------------------------------------------------
// QKV projection via MFMA. Q,K row-major bf16. V in FRAGMENT ORDER (layout
// hardware-verified in r10): per 32-key tile tg, chunk c = ncv*2 + step
// (d-tile, k-half), a 1KB block of the exact 64-lane x 16B PV A-fragment:
//   Vf[tg*8192 + c*512 + lane*8 + j] = V[key = step*16 + (lane>>5)*8 + j]
//                                       [d = ncv*32 + (lane&31)]
// ---------------------------------------------------------------------------
__global__ __launch_bounds__(256) void proj_mfma(
    const float* __restrict__ X, const float* __restrict__ Wq,
    const float* __restrict__ Wk, const float* __restrict__ Wv,
    unsigned short* __restrict__ Qb, unsigned short* __restrict__ Kb,
    unsigned short* __restrict__ Vf)
{
    __shared__ char Wl[32768];
    const int z = blockIdx.z;
    const float* W = (z == 0) ? Wq : (z == 1) ? Wk : Wv;
    const int r0 = blockIdx.x * 64;
    const int c0 = blockIdx.y * 64;
    const int t = threadIdx.x, w = t >> 6, l = t & 63;
    const int lo = l & 15, hi = l >> 4;

    #pragma unroll
    for (int i = 0; i < 16; ++i) {
        int e4 = t + i * 256;
        int col = e4 >> 6, kk4 = e4 & 63;
        float4 f = *(const float4*)&W[(size_t)(c0 + col) * D + kk4 * 4];
        unsigned long long v = (unsigned long long)pk2(f.x, f.y)
                             | ((unsigned long long)pk2(f.z, f.w) << 32);
        *(unsigned long long*)(Wl + col * 512 + ((kk4 * 8) ^ ((col & 7) << 4))) = v;
    }
    __syncthreads();

    bf16x8 xf[8];
    {
        const float* xr = X + (size_t)(r0 + w * 16 + lo) * D;
        #pragma unroll
        for (int ks = 0; ks < 8; ++ks) {
            float4 a = *(const float4*)(xr + ks * 32 + hi * 8);
            float4 b = *(const float4*)(xr + ks * 32 + hi * 8 + 4);
            bf16x8 v;
            v[0] = (short)f2b(a.x); v[1] = (short)f2b(a.y);
            v[2] = (short)f2b(a.z); v[3] = (short)f2b(a.w);
            v[4] = (short)f2b(b.x); v[5] = (short)f2b(b.y);
            v[6] = (short)f2b(b.z); v[7] = (short)f2b(b.w);
            xf[ks] = v;
        }
    }

    f32x4 acc[4];
    #pragma unroll
    for (int nc = 0; nc < 4; ++nc) acc[nc] = (f32x4){0.f, 0.f, 0.f, 0.f};
    #pragma unroll
    for (int ks = 0; ks < 8; ++ks) {
        #pragma unroll
        for (int nc = 0; nc < 4; ++nc) {
            int col = nc * 16 + lo;
            bf16x8 wf = *(const bf16x8*)(Wl + col * 512 +
                                         ((ks * 64 + hi * 16) ^ ((col & 7) << 4)));
            acc[nc] = MFMA16(xf[ks], wf, acc[nc]);
        }
    }

    if (z < 2) {
        unsigned short* Y = z ? Kb : Qb;
        #pragma unroll
        for (int nc = 0; nc < 4; ++nc)
            #pragma unroll
            for (int r = 0; r < 4; ++r)
                Y[(size_t)(r0 + w * 16 + hi * 4 + r) * D + c0 + nc * 16 + lo] = f2b(acc[nc][r]);
    } else {
        // V fragment-order (4 consecutive keys -> one 8B store)
        const int keyb = r0 + w * 16 + hi * 4;
        const int tile = keyb >> 5, kr = keyb & 31;
        const int step = kr >> 4, h1v = (kr >> 3) & 1, jb = kr & 7;
        #pragma unroll
        for (int nc = 0; nc < 4; ++nc) {
            int d = c0 + nc * 16 + lo;
            int ncv = d >> 5, dr = d & 31;
            unsigned long long v = (unsigned long long)pk2(acc[nc][0], acc[nc][1])
                                 | ((unsigned long long)pk2(acc[nc][2], acc[nc][3]) << 32);
            *(unsigned long long*)&Vf[(size_t)tile * 8192 + (ncv * 2 + step) * 512
                                      + (h1v * 32 + dr) * 8 + jb] = v;
        }
    }
}

// ---------------------------------------------------------------------------
// Flash attention: 4 waves x 32 q-rows, KBLK=32, 32x32x16 MFMA, K-split,
// 2 blocks/CU. K staged in LDS (dbuf 2x16K, counted vmcnt(4)); V read
// DIRECTLY from global fragment-order Vf (coalesced 1KB/instr, L1-resident
// tile, transient 8-frag register batches -> no spill). LDS: 32768 B.
// ---------------------------------------------------------------------------
template <int KSPLIT>
__global__ __launch_bounds__(256, 2) void attn_mfma(
    const unsigned short* __restrict__ Qb,
    const unsigned short* __restrict__ Kb,
    const unsigned short* __restrict__ Vf,
    unsigned short* __restrict__ Opart,
    float2* __restrict__ ml)
{
    extern __shared__ char smem[];                 // K dbuf 2x16K
    const int t = threadIdx.x;
    const int w = t >> 6;
    const int l = t & 63;
    const int r = l & 31;                          // A-row (key/d) & q-col
    const int hi1 = l >> 5;
    const int bid = blockIdx.x;
    const int split = bid % KSPLIT;
    const int xblk = bid / KSPLIT;
    const int q0 = xblk * QBLK + w * 32;
    const int kbase = split * (N / KSPLIT);
    const int NTS = N / KSPLIT / KBLK;
    const int p0 = bid & (NTS - 1);                // tile-start rotation (dephase)

    // K staging source offsets (pk row permutation + chunk swizzle), once.
    unsigned ksoff[4];
    #pragma unroll
    for (int i = 0; i < 4; ++i) {
        int c = t + i * 256;                       // 16B chunk id, 0..1023
        int rr = c >> 5, xc = c & 31;
        int pk = (rr & 0x13) | ((rr & 4) << 1) | ((rr & 8) >> 1);
        ksoff[i] = (unsigned)(pk * D + (xc ^ (rr & 7)) * 8);
    }

    auto stageK = [&](char* kbuf, int tile) {
        const unsigned koff = (unsigned)(kbase + tile * KBLK) * D;
        #pragma unroll
        for (int i = 0; i < 4; ++i)
            __builtin_amdgcn_global_load_lds(
                (const __attribute__((address_space(1))) void*)(Kb + koff + ksoff[i]),
                (__attribute__((address_space(3))) void*)(kbuf + (t + i * 256) * 16), 16, 0, 0);
    };

    // resident Q B-frags: col q = q0 + r, k = ks*16 + hi1*8 + j
    bf16x8 qf[16];
    {
        const unsigned short* qrow = Qb + (size_t)(q0 + r) * D;
        #pragma unroll
        for (int ks = 0; ks < 16; ++ks)
            qf[ks] = *(const bf16x8*)(qrow + ks * 16 + hi1 * 8);
    }

    // per-lane V fragment base
    const unsigned short* Vfl = Vf + (size_t)l * 8;

    // prologue: 2-deep K prefetch (rotated tile order)
    stageK(smem, p0);
    stageK(smem + 16384, (p0 + 1) & (NTS - 1));

    f32x16 Oacc[8];
    #pragma unroll
    for (int nc = 0; nc < 8; ++nc)
        #pragma unroll
        for (int e = 0; e < 16; ++e) Oacc[nc][e] = 0.f;
    float m_run = -INFINITY, l_run = 0.f;
    const float scale2 = 0.09016994f;              // (1/16) * log2(e)

    for (int tt = 0; tt < NTS; ++tt) {
        const int cur = tt & 1;
        char* Kl = smem + cur * 16384;
        const int tile = (p0 + tt) & (NTS - 1);
        const size_t voff = ((size_t)(kbase / KBLK) + tile) * 8192;

        // ---- wait own K-stage of tile tt (4 younger allowed), converge
        if (tt + 1 == NTS) asm volatile("s_waitcnt vmcnt(0)" ::: "memory");
        else               asm volatile("s_waitcnt vmcnt(4)" ::: "memory");
        BAR(); CFENCE();

        // ---- S^T = K . Q^T : batch-load 8 K-frags, MFMA burst, x2
        f32x16 sacc;
        #pragma unroll
        for (int e = 0; e < 16; ++e) sacc[e] = 0.f;

        bf16x8 kf8[8];
        #pragma unroll
        for (int j = 0; j < 8; ++j)
            kf8[j] = *(const bf16x8*)(Kl + r * 512 + (((j * 2 + hi1) ^ (r & 7)) * 16));
        __builtin_amdgcn_s_setprio(1);
        #pragma unroll
        for (int j = 0; j < 8; ++j)
            sacc = MFMA32(kf8[j], qf[j], sacc);
        __builtin_amdgcn_s_setprio(0);

        bf16x8 kg8[8];
        #pragma unroll
        for (int j = 0; j < 8; ++j)
            kg8[j] = *(const bf16x8*)(Kl + r * 512 + ((((8 + j) * 2 + hi1) ^ (r & 7)) * 16));
        __builtin_amdgcn_s_setprio(1);
        #pragma unroll
        for (int j = 0; j < 8; ++j)
            sacc = MFMA32(kg8[j], qf[8 + j], sacc);
        __builtin_amdgcn_s_setprio(0);

        // ---- V-frag batch 1 issued now; latency hides under softmax
        bf16x8 vf8[8];
        #pragma unroll
        for (int c = 0; c < 8; ++c)
            vf8[c] = *(const bf16x8*)(Vfl + voff + c * 512);

        // ---- softmax (per-lane: one q per lane; keys split lane / lane+32)
        float m0 = fmaxf(fmaxf(sacc[0], sacc[1]),   fmaxf(sacc[2], sacc[3]));
        float m1 = fmaxf(fmaxf(sacc[4], sacc[5]),   fmaxf(sacc[6], sacc[7]));
        float m2 = fmaxf(fmaxf(sacc[8], sacc[9]),   fmaxf(sacc[10], sacc[11]));
        float m3 = fmaxf(fmaxf(sacc[12], sacc[13]), fmaxf(sacc[14], sacc[15]));
        float pm = fmaxf(fmaxf(m0, m1), fmaxf(m2, m3)) * scale2;

        bool need = pm > m_run + 11.0f;
        if (__builtin_expect(__any(need), 0)) {
            float m2x = fmaxf(pm, __shfl_xor(pm, 32));
            float m_new = fmaxf(m_run, m2x);
            float corr = exp2f(m_run - m_new);
            m_run = m_new;
            l_run *= corr;
            #pragma unroll
            for (int nc = 0; nc < 8; ++nc)
                #pragma unroll
                for (int e = 0; e < 16; ++e) Oacc[nc][e] *= corr;  // per-lane scalar
        }

        // ---- P = 2^(S*scale2 - m), packed in-register (linear order feeds PV)
        bf16x8 pb[2];
        float sum = 0.f;
        #pragma unroll
        for (int s1 = 0; s1 < 2; ++s1) {
            union { unsigned u[4]; bf16x8 v; } uu;
            #pragma unroll
            for (int j2 = 0; j2 < 4; ++j2) {
                float a = __builtin_amdgcn_exp2f(sacc[s1 * 8 + j2 * 2]     * scale2 - m_run);
                float b = __builtin_amdgcn_exp2f(sacc[s1 * 8 + j2 * 2 + 1] * scale2 - m_run);
                sum += a + b;
                uu.u[j2] = cvtpk(a, b);
            }
            pb[s1] = uu.v;
        }

        // ---- PV half 1 (d-tiles 0..3)
        __builtin_amdgcn_s_setprio(1);
        #pragma unroll
        for (int nc = 0; nc < 4; ++nc) {
            Oacc[nc] = MFMA32(vf8[nc * 2 + 0], pb[0], Oacc[nc]);
            Oacc[nc] = MFMA32(vf8[nc * 2 + 1], pb[1], Oacc[nc]);
        }
        __builtin_amdgcn_s_setprio(0);

        // ---- V-frag batch 2 (reuses batch-1 registers), then PV half 2
        bf16x8 vg8[8];
        #pragma unroll
        for (int c = 0; c < 8; ++c)
            vg8[c] = *(const bf16x8*)(Vfl + voff + (8 + c) * 512);
        __builtin_amdgcn_s_setprio(1);
        #pragma unroll
        for (int nc = 0; nc < 4; ++nc) {
            Oacc[nc + 4] = MFMA32(vg8[nc * 2 + 0], pb[0], Oacc[nc + 4]);
            Oacc[nc + 4] = MFMA32(vg8[nc * 2 + 1], pb[1], Oacc[nc + 4]);
        }
        __builtin_amdgcn_s_setprio(0);

        l_run += sum;

        // ---- converge, then restage Kbuf[cur] with tile tt+2 (no drain)
        CFENCE(); BAR(); CFENCE();
        if (tt + 2 < NTS)
            stageK(Kl, (p0 + tt + 2) & (NTS - 1));
    }

    // ---- epilogue: combine lane/lane+32 l partials; write O~ + (m, l)
    l_run += __shfl_xor(l_run, 32);
    const size_t orow = ((size_t)split * N + q0 + r) * D;
    #pragma unroll
    for (int nc = 0; nc < 8; ++nc)
        #pragma unroll
        for (int g = 0; g < 4; ++g) {
            unsigned long long v =
                  (unsigned long long)pk2(Oacc[nc][g * 4 + 0], Oacc[nc][g * 4 + 1])
                | ((unsigned long long)pk2(Oacc[nc][g * 4 + 2], Oacc[nc][g * 4 + 3]) << 32);
            *(unsigned long long*)&Opart[orow + nc * 32 + g * 8 + hi1 * 4] = v;
        }
    if (l < 32)
        ml[(size_t)split * N + q0 + r] = make_float2(m_run, l_run);
}

// ---------------------------------------------------------------------------
// Combine (base-2 m): O = sum_i 2^(m_i-M) O~_i / sum_i 2^(m_i-M) l_i
// ---------------------------------------------------------------------------
__global__ __launch_bounds__(256) void combine_kernel(
    const unsigned short* __restrict__ Opart, const float2* __restrict__ ml,
    float* __restrict__ out, int nsplit)
{
    int idx = blockIdx.x * 256 + threadIdx.x;
    int q = idx >> 5;
    int d0 = (idx & 31) * 8;

    float M = -INFINITY;
    for (int i = 0; i < nsplit; ++i) M = fmaxf(M, ml[(size_t)i * N + q].x);
    float L = 0.f;
    float acc[8] = {};
    for (int i = 0; i < nsplit; ++i) {
        float2 v = ml[(size_t)i * N + q];
        float wgt = exp2f(v.x - M);
        L += wgt * v.y;
        bf16x8 ov = *(const bf16x8*)&Opart[((size_t)i * N + q) * D + d0];
        #pragma unroll
        for (int j = 0; j < 8; ++j) acc[j] += wgt * b2f(ov[j]);
    }
    float r = 1.f / L;
    #pragma unroll
    for (int j = 0; j < 8; ++j) out[(size_t)q * D + d0 + j] = acc[j] * r;
}

extern "C" void kernel_launch(void* const* d_in, const int* in_sizes, int n_in,
                              void* d_out, int out_size, void* d_ws, size_t ws_size,
                              hipStream_t stream) {
    const float* X  = (const float*)d_in[0];
    const float* Wq = (const float*)d_in[1];
    const float* Wk = (const float*)d_in[2];
    const float* Wv = (const float*)d_in[3];

    unsigned short* ws = (unsigned short*)d_ws;
    const size_t ndq = (size_t)N * D;
    unsigned short* Qb = ws;
    unsigned short* Kb = ws + ndq;
    unsigned short* Vf = ws + 2 * ndq;
    unsigned short* Opart = ws + 3 * ndq;

    auto need = [ndq](int ks) {
        return (size_t)(3 + ks) * ndq * 2 + (size_t)ks * N * 8;
    };
    const int ksplit = (ws_size >= need(8)) ? 8 : (ws_size >= need(4)) ? 4 : 2;
    float2* ml = (float2*)(ws + (3 + ksplit) * ndq);

    (void)hipFuncSetAttribute((const void*)attn_mfma<8>,
                              hipFuncAttributeMaxDynamicSharedMemorySize, 32768);
    (void)hipFuncSetAttribute((const void*)attn_mfma<4>,
                              hipFuncAttributeMaxDynamicSharedMemorySize, 32768);
    (void)hipFuncSetAttribute((const void*)attn_mfma<2>,
                              hipFuncAttributeMaxDynamicSharedMemorySize, 32768);

    proj_mfma<<<dim3(N / 64, D / 64, 3), 256, 0, stream>>>(X, Wq, Wk, Wv, Qb, Kb, Vf);
    if (ksplit == 8)
        attn_mfma<8><<<dim3((N / QBLK) * 8), 256, 32768, stream>>>(Qb, Kb, Vf, Opart, ml);
    else if (ksplit == 4)
        attn_mfma<4><<<dim3((N / QBLK) * 4), 256, 32768, stream>>>(Qb, Kb, Vf, Opart, ml);
    else
        attn_mfma<2><<<dim3((N / QBLK) * 2), 256, 32768, stream>>>(Qb, Kb, Vf, Opart, ml);
    combine_kernel<<<(N * D / 8) / 256, 256, 0, stream>>>(Opart, ml, (float*)d_out, ksplit);
}

// Round 13
// 122.952 us; speedup vs baseline: 1.1040x; 1.1040x over previous
//
#include <hip/hip_runtime.h>
#include <math.h>

#define N 8192
#define D 256
#define QBLK 256          // 8 waves x 32 q-rows, 1 block/CU
#define KBLK 32

typedef float f32x4 __attribute__((ext_vector_type(4)));
typedef float f32x16 __attribute__((ext_vector_type(16)));
typedef short bf16x8 __attribute__((ext_vector_type(8)));

#define MFMA16(a, b, c) __builtin_amdgcn_mfma_f32_16x16x32_bf16((a), (b), (c), 0, 0, 0)
#define MFMA32(a, b, c) __builtin_amdgcn_mfma_f32_32x32x16_bf16((a), (b), (c), 0, 0, 0)
#define BAR() __builtin_amdgcn_s_barrier()
#define CFENCE() asm volatile("" ::: "memory")

__device__ __forceinline__ unsigned short f2b(float f) {
    unsigned u = __builtin_bit_cast(unsigned, f);
    u = u + 0x7fffu + ((u >> 16) & 1u);            // RNE
    return (unsigned short)(u >> 16);
}
__device__ __forceinline__ unsigned pk2(float a, float b) {
    return (unsigned)f2b(a) | ((unsigned)f2b(b) << 16);
}
__device__ __forceinline__ unsigned cvtpk(float a, float b) {
    unsigned r;
    asm("v_cvt_pk_bf16_f32 %0, %1, %2" : "=v"(r) : "v"(a), "v"(b));
    return r;
}
__device__ __forceinline__ float b2f(short s) {
    unsigned x = ((unsigned)(unsigned short)s) << 16;
    return __builtin_bit_cast(float, x);
}

// ---------------------------------------------------------------------------
// QKV projection via MFMA (r8/r11 version — verified). Q,K row-major bf16;
// V transposed (Vt[d][key]).
// ---------------------------------------------------------------------------
__global__ __launch_bounds__(256) void proj_mfma(
    const float* __restrict__ X, const float* __restrict__ Wq,
    const float* __restrict__ Wk, const float* __restrict__ Wv,
    unsigned short* __restrict__ Qb, unsigned short* __restrict__ Kb,
    unsigned short* __restrict__ Vt)
{
    __shared__ char Wl[32768];
    const int z = blockIdx.z;
    const float* W = (z == 0) ? Wq : (z == 1) ? Wk : Wv;
    const int r0 = blockIdx.x * 64;
    const int c0 = blockIdx.y * 64;
    const int t = threadIdx.x, w = t >> 6, l = t & 63;
    const int lo = l & 15, hi = l >> 4;

    #pragma unroll
    for (int i = 0; i < 16; ++i) {
        int e4 = t + i * 256;
        int col = e4 >> 6, kk4 = e4 & 63;
        float4 f = *(const float4*)&W[(size_t)(c0 + col) * D + kk4 * 4];
        unsigned long long v = (unsigned long long)pk2(f.x, f.y)
                             | ((unsigned long long)pk2(f.z, f.w) << 32);
        *(unsigned long long*)(Wl + col * 512 + ((kk4 * 8) ^ ((col & 7) << 4))) = v;
    }
    __syncthreads();

    bf16x8 xf[8];
    {
        const float* xr = X + (size_t)(r0 + w * 16 + lo) * D;
        #pragma unroll
        for (int ks = 0; ks < 8; ++ks) {
            float4 a = *(const float4*)(xr + ks * 32 + hi * 8);
            float4 b = *(const float4*)(xr + ks * 32 + hi * 8 + 4);
            bf16x8 v;
            v[0] = (short)f2b(a.x); v[1] = (short)f2b(a.y);
            v[2] = (short)f2b(a.z); v[3] = (short)f2b(a.w);
            v[4] = (short)f2b(b.x); v[5] = (short)f2b(b.y);
            v[6] = (short)f2b(b.z); v[7] = (short)f2b(b.w);
            xf[ks] = v;
        }
    }

    f32x4 acc[4];
    #pragma unroll
    for (int nc = 0; nc < 4; ++nc) acc[nc] = (f32x4){0.f, 0.f, 0.f, 0.f};
    #pragma unroll
    for (int ks = 0; ks < 8; ++ks) {
        #pragma unroll
        for (int nc = 0; nc < 4; ++nc) {
            int col = nc * 16 + lo;
            bf16x8 wf = *(const bf16x8*)(Wl + col * 512 +
                                         ((ks * 64 + hi * 16) ^ ((col & 7) << 4)));
            acc[nc] = MFMA16(xf[ks], wf, acc[nc]);
        }
    }

    if (z < 2) {
        unsigned short* Y = z ? Kb : Qb;
        #pragma unroll
        for (int nc = 0; nc < 4; ++nc)
            #pragma unroll
            for (int r = 0; r < 4; ++r)
                Y[(size_t)(r0 + w * 16 + hi * 4 + r) * D + c0 + nc * 16 + lo] = f2b(acc[nc][r]);
    } else {
        #pragma unroll
        for (int nc = 0; nc < 4; ++nc) {
            unsigned long long v = (unsigned long long)pk2(acc[nc][0], acc[nc][1])
                                 | ((unsigned long long)pk2(acc[nc][2], acc[nc][3]) << 32);
            *(unsigned long long*)&Vt[(size_t)(c0 + nc * 16 + lo) * N + r0 + w * 16 + hi * 4] = v;
        }
    }
}

// ---------------------------------------------------------------------------
// Flash attention: 8 waves x 32 q-rows (512 thr, 1 block/CU), KBLK=32,
// 32x32x16 MFMA, K-split. TRIPLE-buffered K+V LDS (3 x 32KB = 96KB):
// stage(t+2) issued at TOP of iter t (stage-to-use = 2 iters), counted
// vmcnt(8), two bare barriers/iter, batched ds_reads + setprio'd MFMA
// clusters (phase-interleaved schedule; T3+T4 regime).
// ---------------------------------------------------------------------------
template <int KSPLIT>
__global__ __launch_bounds__(512, 2) void attn_mfma(
    const unsigned short* __restrict__ Qb,
    const unsigned short* __restrict__ Kb,
    const unsigned short* __restrict__ Vt,
    unsigned short* __restrict__ Opart,
    float2* __restrict__ ml)
{
    extern __shared__ char smem[];                 // buf b: K @ b*32768, V @ +16384
    const int t = threadIdx.x;                     // 0..511
    const int w = t >> 6;
    const int l = t & 63;
    const int r = l & 31;                          // A-row (key/d) & q-col
    const int hi1 = l >> 5;
    const int bid = blockIdx.x;
    const int split = bid % KSPLIT;                // XCD-aligned
    const int xblk = bid / KSPLIT;
    const int q0 = xblk * QBLK + w * 32;
    const int kbase = split * (N / KSPLIT);
    const int NTS = N / KSPLIT / KBLK;
    const int p0 = xblk & (NTS - 1);               // tile-start rotation

    // staging source offsets (2 chunks per thread for K, 2 for V), once.
    unsigned ksoff[2], vsoff[2];
    #pragma unroll
    for (int i = 0; i < 2; ++i) {
        int c = t + i * 512;                       // 16B chunk id, 0..1023
        int rr = c >> 5, xc = c & 31;
        int pk = (rr & 0x13) | ((rr & 4) << 1) | ((rr & 8) >> 1);
        ksoff[i] = (unsigned)(pk * D + (xc ^ (rr & 7)) * 8);
        int dd = c >> 2, x2 = c & 3;
        vsoff[i] = (unsigned)(dd * N + (x2 ^ ((dd >> 1) & 3)) * 8);
    }

    auto stage = [&](char* buf, int tile) {        // 4 global_load_lds / thread
        const unsigned kv0 = (unsigned)(kbase + tile * KBLK);
        const unsigned koff = kv0 * D;
        #pragma unroll
        for (int i = 0; i < 2; ++i)
            __builtin_amdgcn_global_load_lds(
                (const __attribute__((address_space(1))) void*)(Kb + koff + ksoff[i]),
                (__attribute__((address_space(3))) void*)(buf + (t + i * 512) * 16), 16, 0, 0);
        #pragma unroll
        for (int i = 0; i < 2; ++i)
            __builtin_amdgcn_global_load_lds(
                (const __attribute__((address_space(1))) void*)(Vt + kv0 + vsoff[i]),
                (__attribute__((address_space(3))) void*)(buf + 16384 + (t + i * 512) * 16), 16, 0, 0);
    };

    // resident Q B-frags: col q = q0 + r, k = ks*16 + hi1*8 + j
    bf16x8 qf[16];
    {
        const unsigned short* qrow = Qb + (size_t)(q0 + r) * D;
        #pragma unroll
        for (int ks = 0; ks < 16; ++ks)
            qf[ks] = *(const bf16x8*)(qrow + ks * 16 + hi1 * 8);
    }

    // prologue: 2-deep prefetch into bufs 0,1 (rotated tile order)
    stage(smem, p0);
    stage(smem + 32768, (p0 + 1) & (NTS - 1));

    f32x16 Oacc[8];
    #pragma unroll
    for (int nc = 0; nc < 8; ++nc)
        #pragma unroll
        for (int e = 0; e < 16; ++e) Oacc[nc][e] = 0.f;
    float m_run = -INFINITY, l_run = 0.f;
    const float scale2 = 0.09016994f;              // (1/16) * log2(e)

    int bcur = 0;                                  // buf index = tt % 3
    for (int tt = 0; tt < NTS; ++tt) {
        char* Kl = smem + bcur * 32768;
        char* Vl = Kl + 16384;

        // ---- issue stage(t+2) into buf[(tt+2)%3] (read-free since end of t-1)
        if (tt + 2 < NTS) {
            int bnx = bcur + 2; if (bnx >= 3) bnx -= 3;
            stage(smem + bnx * 32768, (p0 + tt + 2) & (NTS - 1));
            asm volatile("s_waitcnt vmcnt(8)" ::: "memory");   // buf[tt%3] ready
        } else if (tt + 1 < NTS) {
            asm volatile("s_waitcnt vmcnt(4)" ::: "memory");
        } else {
            asm volatile("s_waitcnt vmcnt(0)" ::: "memory");
        }
        BAR(); CFENCE();

        // ---- QK phase: 2 x {batch-load 8 K-frags, MFMA cluster}
        f32x16 sacc;
        #pragma unroll
        for (int e = 0; e < 16; ++e) sacc[e] = 0.f;

        bf16x8 kf8[8];
        #pragma unroll
        for (int j = 0; j < 8; ++j)
            kf8[j] = *(const bf16x8*)(Kl + r * 512 + (((j * 2 + hi1) ^ (r & 7)) * 16));
        __builtin_amdgcn_s_setprio(1);
        #pragma unroll
        for (int j = 0; j < 8; ++j)
            sacc = MFMA32(kf8[j], qf[j], sacc);
        __builtin_amdgcn_s_setprio(0);

        bf16x8 kg8[8];
        #pragma unroll
        for (int j = 0; j < 8; ++j)
            kg8[j] = *(const bf16x8*)(Kl + r * 512 + ((((8 + j) * 2 + hi1) ^ (r & 7)) * 16));
        __builtin_amdgcn_s_setprio(1);
        #pragma unroll
        for (int j = 0; j < 8; ++j)
            sacc = MFMA32(kg8[j], qf[8 + j], sacc);
        __builtin_amdgcn_s_setprio(0);

        // ---- softmax (per-lane; defer cross-lane to rare overflow)
        float m0 = fmaxf(fmaxf(sacc[0], sacc[1]),   fmaxf(sacc[2], sacc[3]));
        float m1 = fmaxf(fmaxf(sacc[4], sacc[5]),   fmaxf(sacc[6], sacc[7]));
        float m2 = fmaxf(fmaxf(sacc[8], sacc[9]),   fmaxf(sacc[10], sacc[11]));
        float m3 = fmaxf(fmaxf(sacc[12], sacc[13]), fmaxf(sacc[14], sacc[15]));
        float pm = fmaxf(fmaxf(m0, m1), fmaxf(m2, m3)) * scale2;

        bool need = pm > m_run + 11.0f;
        if (__builtin_expect(__any(need), 0)) {
            float m2x = fmaxf(pm, __shfl_xor(pm, 32));
            float m_new = fmaxf(m_run, m2x);
            float corr = exp2f(m_run - m_new);
            m_run = m_new;
            l_run *= corr;
            #pragma unroll
            for (int nc = 0; nc < 8; ++nc)
                #pragma unroll
                for (int e = 0; e < 16; ++e) Oacc[nc][e] *= corr;
        }

        // ---- P = 2^(S*scale2 - m), packed in-register
        bf16x8 pb[2];
        float sum = 0.f;
        #pragma unroll
        for (int s1 = 0; s1 < 2; ++s1) {
            union { unsigned u[4]; bf16x8 v; } uu;
            #pragma unroll
            for (int j2 = 0; j2 < 4; ++j2) {
                float a = __builtin_amdgcn_exp2f(sacc[s1 * 8 + j2 * 2]     * scale2 - m_run);
                float b = __builtin_amdgcn_exp2f(sacc[s1 * 8 + j2 * 2 + 1] * scale2 - m_run);
                sum += a + b;
                uu.u[j2] = cvtpk(a, b);
            }
            pb[s1] = uu.v;
        }

        // ---- PV phase: 2 x {batch-load 8 V-frags, MFMA cluster}
        bf16x8 vf8[8];
        #pragma unroll
        for (int nc = 0; nc < 4; ++nc) {
            const char* vrow = Vl + (nc * 32 + r) * 64;
            vf8[nc * 2 + 0] = *(const bf16x8*)(vrow + (((0 + hi1) ^ ((r >> 1) & 3)) * 16));
            vf8[nc * 2 + 1] = *(const bf16x8*)(vrow + (((2 + hi1) ^ ((r >> 1) & 3)) * 16));
        }
        __builtin_amdgcn_s_setprio(1);
        #pragma unroll
        for (int nc = 0; nc < 4; ++nc) {
            Oacc[nc] = MFMA32(vf8[nc * 2 + 0], pb[0], Oacc[nc]);
            Oacc[nc] = MFMA32(vf8[nc * 2 + 1], pb[1], Oacc[nc]);
        }
        __builtin_amdgcn_s_setprio(0);

        bf16x8 vg8[8];
        #pragma unroll
        for (int nc = 0; nc < 4; ++nc) {
            const char* vrow = Vl + ((nc + 4) * 32 + r) * 64;
            vg8[nc * 2 + 0] = *(const bf16x8*)(vrow + (((0 + hi1) ^ ((r >> 1) & 3)) * 16));
            vg8[nc * 2 + 1] = *(const bf16x8*)(vrow + (((2 + hi1) ^ ((r >> 1) & 3)) * 16));
        }
        __builtin_amdgcn_s_setprio(1);
        #pragma unroll
        for (int nc = 0; nc < 4; ++nc) {
            Oacc[nc + 4] = MFMA32(vg8[nc * 2 + 0], pb[0], Oacc[nc + 4]);
            Oacc[nc + 4] = MFMA32(vg8[nc * 2 + 1], pb[1], Oacc[nc + 4]);
        }
        __builtin_amdgcn_s_setprio(0);

        l_run += sum;

        // ---- end-of-iter convergence: protects buf[tt%3] from next restage
        CFENCE(); BAR(); CFENCE();
        ++bcur; if (bcur == 3) bcur = 0;
    }

    // ---- epilogue: combine lane/lane+32 l partials; write O~ + (m, l)
    l_run += __shfl_xor(l_run, 32);
    const size_t orow = ((size_t)split * N + q0 + r) * D;
    #pragma unroll
    for (int nc = 0; nc < 8; ++nc)
        #pragma unroll
        for (int g = 0; g < 4; ++g) {
            unsigned long long v =
                  (unsigned long long)pk2(Oacc[nc][g * 4 + 0], Oacc[nc][g * 4 + 1])
                | ((unsigned long long)pk2(Oacc[nc][g * 4 + 2], Oacc[nc][g * 4 + 3]) << 32);
            *(unsigned long long*)&Opart[orow + nc * 32 + g * 8 + hi1 * 4] = v;
        }
    if (l < 32)
        ml[(size_t)split * N + q0 + r] = make_float2(m_run, l_run);
}

// ---------------------------------------------------------------------------
// Combine (base-2 m): O = sum_i 2^(m_i-M) O~_i / sum_i 2^(m_i-M) l_i
// ---------------------------------------------------------------------------
__global__ __launch_bounds__(256) void combine_kernel(
    const unsigned short* __restrict__ Opart, const float2* __restrict__ ml,
    float* __restrict__ out, int nsplit)
{
    int idx = blockIdx.x * 256 + threadIdx.x;
    int q = idx >> 5;
    int d0 = (idx & 31) * 8;

    float M = -INFINITY;
    for (int i = 0; i < nsplit; ++i) M = fmaxf(M, ml[(size_t)i * N + q].x);
    float L = 0.f;
    float acc[8] = {};
    for (int i = 0; i < nsplit; ++i) {
        float2 v = ml[(size_t)i * N + q];
        float wgt = exp2f(v.x - M);
        L += wgt * v.y;
        bf16x8 ov = *(const bf16x8*)&Opart[((size_t)i * N + q) * D + d0];
        #pragma unroll
        for (int j = 0; j < 8; ++j) acc[j] += wgt * b2f(ov[j]);
    }
    float r = 1.f / L;
    #pragma unroll
    for (int j = 0; j < 8; ++j) out[(size_t)q * D + d0 + j] = acc[j] * r;
}

extern "C" void kernel_launch(void* const* d_in, const int* in_sizes, int n_in,
                              void* d_out, int out_size, void* d_ws, size_t ws_size,
                              hipStream_t stream) {
    const float* X  = (const float*)d_in[0];
    const float* Wq = (const float*)d_in[1];
    const float* Wk = (const float*)d_in[2];
    const float* Wv = (const float*)d_in[3];

    unsigned short* ws = (unsigned short*)d_ws;
    const size_t ndq = (size_t)N * D;
    unsigned short* Qb = ws;
    unsigned short* Kb = ws + ndq;
    unsigned short* Vt = ws + 2 * ndq;
    unsigned short* Opart = ws + 3 * ndq;

    auto need = [ndq](int ks) {
        return (size_t)(3 + ks) * ndq * 2 + (size_t)ks * N * 8;
    };
    const int ksplit = (ws_size >= need(8)) ? 8 : (ws_size >= need(4)) ? 4 : 2;
    float2* ml = (float2*)(ws + (3 + ksplit) * ndq);

    (void)hipFuncSetAttribute((const void*)attn_mfma<8>,
                              hipFuncAttributeMaxDynamicSharedMemorySize, 98304);
    (void)hipFuncSetAttribute((const void*)attn_mfma<4>,
                              hipFuncAttributeMaxDynamicSharedMemorySize, 98304);
    (void)hipFuncSetAttribute((const void*)attn_mfma<2>,
                              hipFuncAttributeMaxDynamicSharedMemorySize, 98304);

    proj_mfma<<<dim3(N / 64, D / 64, 3), 256, 0, stream>>>(X, Wq, Wk, Wv, Qb, Kb, Vt);
    if (ksplit == 8)
        attn_mfma<8><<<dim3((N / QBLK) * 8), 512, 98304, stream>>>(Qb, Kb, Vt, Opart, ml);
    else if (ksplit == 4)
        attn_mfma<4><<<dim3((N / QBLK) * 4), 512, 98304, stream>>>(Qb, Kb, Vt, Opart, ml);
    else
        attn_mfma<2><<<dim3((N / QBLK) * 2), 512, 98304, stream>>>(Qb, Kb, Vt, Opart, ml);
    combine_kernel<<<(N * D / 8) / 256, 256, 0, stream>>>(Opart, ml, (float*)d_out, ksplit);
}